// Round 4
// baseline (942.371 us; speedup 1.0000x reference)
//
#include <hip/hip_runtime.h>

// AdultConnectomeNetwork: 3 layers of xt = A_sp @ (W_sp @ xt) + bias.
// Round 4:
//  - Two-phase bucketed COO->CSR sort. Phase 1 appends edges to coarse
//    buckets (row>>5): per-bucket sequential appends -> L2 write combining
//    (vs round-3 random 16B scatter @ ~1TB/s effective). Phase 2: one block
//    per bucket, in-LDS 32-bin counting sort, coalesced write-back in exact
//    CSR order. Oversized buckets (>CAP, statistically impossible) handled
//    by direct per-row cursor scatter in phase 1.
//  - Edge data split into pkA/pkW float2 arrays {col<<5, val}: each SpMM
//    pass streams 12.8MB not 25.6MB (round-3 float4 carried both vals).
// State layout: xt[N][32] (one 128B line per neuron), lane = batch column.

#define NN 50000
#define NNZ_E 1600000
#define NB (NN * 32)
#define SCAN_BS 256
#define NBLK ((NN + SCAN_BS - 1) / SCAN_BS)   // 196
#define NBUCK ((NN + 31) / 32)                // 1563
#define CAP 3072                              // max in-LDS bucket size

__global__ void zero_counts_kernel(int* __restrict__ counts) {
    int i = blockIdx.x * blockDim.x + threadIdx.x;
    if (i < NN) counts[i] = 0;
}

__global__ void hist_kernel(const int* __restrict__ row, int* __restrict__ counts) {
    int e = blockIdx.x * blockDim.x + threadIdx.x;
    if (e < NNZ_E) atomicAdd(&counts[row[e]], 1);
}

// In-place: counts[i] -> exclusive-scan-within-block; bsum[blk] = block total.
__global__ void scan_block_kernel(int* __restrict__ data, int* __restrict__ bsum) {
    __shared__ int s[SCAN_BS];
    int i = blockIdx.x * SCAN_BS + threadIdx.x;
    int v = (i < NN) ? data[i] : 0;
    s[threadIdx.x] = v;
    __syncthreads();
    for (int off = 1; off < SCAN_BS; off <<= 1) {
        int t = (threadIdx.x >= off) ? s[threadIdx.x - off] : 0;
        __syncthreads();
        s[threadIdx.x] += t;
        __syncthreads();
    }
    if (i < NN) data[i] = s[threadIdx.x] - v;              // exclusive within block
    if (threadIdx.x == SCAN_BS - 1) bsum[blockIdx.x] = s[threadIdx.x];
}

// Parallel exclusive scan of bsum[NBLK] (NBLK <= 256), one block.
__global__ void scan_bsum_kernel(int* __restrict__ bsum) {
    __shared__ int s[SCAN_BS];
    int t = threadIdx.x;
    int v = (t < NBLK) ? bsum[t] : 0;
    s[t] = v;
    __syncthreads();
    for (int off = 1; off < SCAN_BS; off <<= 1) {
        int u = (t >= off) ? s[t - off] : 0;
        __syncthreads();
        s[t] += u;
        __syncthreads();
    }
    if (t < NBLK) bsum[t] = s[t] - v;                      // exclusive
}

__global__ void scan_finalize_kernel(const int* __restrict__ excl,
                                     const int* __restrict__ boff,
                                     int* __restrict__ row_start,
                                     int* __restrict__ cursor) {
    int i = blockIdx.x * blockDim.x + threadIdx.x;
    if (i < NN) {
        int v = excl[i] + boff[i / SCAN_BS];
        row_start[i] = v;
        cursor[i] = v;          // used only by big-bucket fallback
    }
    if (i == 0) row_start[NN] = NNZ_E;
}

// Per-bucket append cursor + big flag (row_start must be complete).
__global__ void bucket_init_kernel(const int* __restrict__ row_start,
                                   int* __restrict__ bcursor,
                                   int* __restrict__ bigflag) {
    int k = blockIdx.x * blockDim.x + threadIdx.x;
    if (k < NBUCK) {
        int s = row_start[k * 32];
        int r1 = k * 32 + 32; if (r1 > NN) r1 = NN;
        int e = row_start[r1];
        bcursor[k] = s;
        bigflag[k] = (e - s > CAP) ? 1 : 0;
    }
}

// Phase 1: append each edge's {key,val} pairs into its coarse bucket region.
// key = (row&31)<<16 | col (col < 65536). Appends are sequential per bucket
// -> active lines stay hot in L2, writes combine.
__global__ void phase1_scatter_kernel(const int* __restrict__ row,
                                      const int* __restrict__ col,
                                      const float* __restrict__ a,
                                      const float* __restrict__ w,
                                      const int* __restrict__ bigflag,
                                      int* __restrict__ bcursor,
                                      int* __restrict__ cursor,
                                      float2* __restrict__ pkA,
                                      float2* __restrict__ pkW) {
    int e = blockIdx.x * blockDim.x + threadIdx.x;
    if (e >= NNZ_E) return;
    int r = row[e];
    int c = col[e];
    int bk = r >> 5;
    if (bigflag[bk]) {                 // statistically-impossible safety path
        int pos = atomicAdd(&cursor[r], 1);
        float cx = __int_as_float(c << 5);
        pkA[pos] = make_float2(cx, a[e]);
        pkW[pos] = make_float2(cx, w[e]);
    } else {
        int pos = atomicAdd(&bcursor[bk], 1);
        float kx = __int_as_float(((r & 31) << 16) | c);
        pkA[pos] = make_float2(kx, a[e]);
        pkW[pos] = make_float2(kx, w[e]);
    }
}

// Phase 2: one block per bucket. Load bucket to LDS, 32-bin counting sort,
// write back in exact CSR order (coalesced region, in-place safe: all global
// reads complete before the barrier preceding the writes).
__global__ __launch_bounds__(256) void bucket_sort_kernel(
        float2* __restrict__ pkA, float2* __restrict__ pkW,
        const int* __restrict__ row_start) {
    int bk = blockIdx.x;
    int r0 = bk * 32;
    int r1 = r0 + 32; if (r1 > NN) r1 = NN;
    int base = row_start[r0];
    int size = row_start[r1] - base;
    if (size > CAP) return;            // handled by phase-1 fallback

    __shared__ float2 sA[CAP];
    __shared__ float2 sW[CAP];
    __shared__ int binc[32];
    __shared__ int bino[32];
    int tid = threadIdx.x;
    if (tid < 32) binc[tid] = 0;
    for (int i = tid; i < size; i += 256) {
        sA[i] = pkA[base + i];
        sW[i] = pkW[base + i];
    }
    __syncthreads();
    for (int i = tid; i < size; i += 256)
        atomicAdd(&binc[__float_as_int(sA[i].x) >> 16], 1);
    __syncthreads();
    if (tid == 0) {
        int acc = 0;
        for (int j = 0; j < 32; ++j) { bino[j] = acc; acc += binc[j]; }
    }
    __syncthreads();
    for (int i = tid; i < size; i += 256) {
        int key = __float_as_int(sA[i].x);
        int p = atomicAdd(&bino[key >> 16], 1);
        float cx = __int_as_float((key & 0xFFFF) << 5);
        pkA[base + p] = make_float2(cx, sA[i].y);
        pkW[base + p] = make_float2(cx, sW[i].y);
    }
}

__global__ void transpose_in_kernel(const float* __restrict__ x,
                                    float* __restrict__ xt) {
    int i = blockIdx.x * blockDim.x + threadIdx.x;  // i = n*32 + b
    if (i < NB) {
        int n = i >> 5;
        int b = i & 31;
        xt[i] = x[b * NN + n];
    }
}

// One 32-lane half-wave per row; lane = batch column. Atomic-free.
__global__ __launch_bounds__(256) void spmm_f2_kernel(
        const float2* __restrict__ pk, const int* __restrict__ row_start,
        const float* __restrict__ in, float* __restrict__ out,
        const float* __restrict__ bias) {
    int t = blockIdx.x * blockDim.x + threadIdx.x;
    int r = t >> 5;
    int b = t & 31;
    if (r >= NN) return;
    int s = row_start[r];
    int e = row_start[r + 1];
    float acc = bias ? bias[r] : 0.0f;
    int i = s;
    for (; i + 8 <= e; i += 8) {
        float2 p[8];
#pragma unroll
        for (int j = 0; j < 8; ++j) p[j] = pk[i + j];
        float g[8];
#pragma unroll
        for (int j = 0; j < 8; ++j) g[j] = in[__float_as_int(p[j].x) + b];
#pragma unroll
        for (int j = 0; j < 8; ++j) acc += p[j].y * g[j];
    }
    for (; i < e; ++i) {
        float2 p = pk[i];
        acc += p.y * in[__float_as_int(p.x) + b];
    }
    out[(r << 5) + b] = acc;
}

__global__ void transpose_out_kernel(const float* __restrict__ xt,
                                     float* __restrict__ out) {
    int i = blockIdx.x * blockDim.x + threadIdx.x;  // i = b*N + n (coalesced write)
    if (i < NB) {
        int b = i / NN;
        int n = i - b * NN;
        out[i] = xt[(n << 5) + b];
    }
}

extern "C" void kernel_launch(void* const* d_in, const int* in_sizes, int n_in,
                              void* d_out, int out_size, void* d_ws, size_t ws_size,
                              hipStream_t stream) {
    const float* x        = (const float*)d_in[0];
    const float* adj_vals = (const float*)d_in[1];
    const float* w_vals   = (const float*)d_in[2];
    const float* bias     = (const float*)d_in[3];
    const int*   row      = (const int*)d_in[4];
    const int*   col      = (const int*)d_in[5];
    float* out = (float*)d_out;

    // Workspace: pkA|pkW (12.8MB ea) | xt|tmp (6.4MB ea) | int arrays (~0.6MB)
    float2* pkA      = (float2*)d_ws;
    float2* pkW      = pkA + NNZ_E;
    float*  xt       = (float*)(pkW + NNZ_E);
    float*  tmp      = xt + NB;
    int*    counts   = (int*)(tmp + NB);
    int*    row_start= counts + NN;
    int*    cursor   = row_start + NN + 4;
    int*    bsum     = cursor + NN;
    int*    bcursor  = bsum + NBLK;
    int*    bigflag  = bcursor + NBUCK;

    const int BS = 256;
    const int grid_n    = (NN + BS - 1) / BS;
    const int grid_nb   = (NB + BS - 1) / BS;
    const int grid_edge = (NNZ_E + BS - 1) / BS;
    const int grid_buck = (NBUCK + BS - 1) / BS;

    // ---- COO -> CSR, bucketed two-phase sort ----
    zero_counts_kernel<<<grid_n, BS, 0, stream>>>(counts);
    hist_kernel<<<grid_edge, BS, 0, stream>>>(row, counts);
    scan_block_kernel<<<NBLK, SCAN_BS, 0, stream>>>(counts, bsum);
    scan_bsum_kernel<<<1, SCAN_BS, 0, stream>>>(bsum);
    scan_finalize_kernel<<<grid_n, BS, 0, stream>>>(counts, bsum, row_start, cursor);
    bucket_init_kernel<<<grid_buck, BS, 0, stream>>>(row_start, bcursor, bigflag);
    phase1_scatter_kernel<<<grid_edge, BS, 0, stream>>>(row, col, adj_vals, w_vals,
                                                        bigflag, bcursor, cursor,
                                                        pkA, pkW);
    bucket_sort_kernel<<<NBUCK, 256, 0, stream>>>(pkA, pkW, row_start);

    // ---- dense passes ----
    transpose_in_kernel<<<grid_nb, BS, 0, stream>>>(x, xt);
    for (int layer = 0; layer < 3; ++layer) {
        spmm_f2_kernel<<<grid_nb, BS, 0, stream>>>(pkW, row_start, xt, tmp, nullptr);
        spmm_f2_kernel<<<grid_nb, BS, 0, stream>>>(pkA, row_start, tmp, xt, bias);
    }
    transpose_out_kernel<<<grid_nb, BS, 0, stream>>>(xt, out);
}

// Round 6
// 451.252 us; speedup vs baseline: 2.0883x; 2.0883x over previous
//
#include <hip/hip_runtime.h>

// AdultConnectomeNetwork: 3 layers of xt = A_sp @ (W_sp @ xt) + bias.
// Round 6: round-5 MSD counting sort (radix structure: per-block precomputed
// offsets, no cross-block shared cursors) HARDENED: every computed store
// index is clamped/guarded so any logic error surfaces as an absmax failure
// (diagnosable) instead of a device fault (round-5 core dump).
//   Pass 1: 196 blocks x 8192-edge chunks; LDS histogram over 391 bins
//     (row>>7); bin-major scanned 391x196 offset matrix gives each block
//     exclusive contiguous runs -> L2 write combining.
//   Pass 2: one block per bin (<=5120 edges, ~62KB LDS), in-LDS placement
//     into exact CSR slots seeded from row_start, dense write-back within
//     the block-private window.
//   Oversized bins (>CAP2, mean+16sigma) fall back to per-row cursor scatter
//   in pass 1 (final positions) and are skipped by pass 2.
// SpMM: one 32-lane half-wave per row, split colK/vals streams, unroll-8.
// State layout: xt[N][32] (one 128B line per neuron), lane = batch column.

#define NN 50000
#define NNZ_E 1600000
#define NB (NN * 32)
#define CHUNK 8192
#define NBLK1 ((NNZ_E + CHUNK - 1) / CHUNK)      // 196
#define NBIN ((NN + 127) / 128)                  // 391
#define NH (NBIN * NBLK1)                        // 76636
#define CAP2 5120
#define SCAN_NBLK_A ((NN + 255) / 256)           // 196
#define SCAN_NBLK_B ((NH + 255) / 256)           // 300

__device__ __forceinline__ int clampi(int v, int hi) {  // [0, hi]
    v = v < 0 ? 0 : v;
    return v > hi ? hi : v;
}

__global__ void zero_counts_kernel(int* __restrict__ counts) {
    int i = blockIdx.x * blockDim.x + threadIdx.x;
    if (i < NN) counts[i] = 0;
}

// Fused: per-row global histogram + per-(block,bin) matrix histogram.
__global__ __launch_bounds__(256) void hist_kernel(const int* __restrict__ row,
                                                   int* __restrict__ counts,
                                                   int* __restrict__ hist1) {
    __shared__ int h[NBIN];
    int blk = blockIdx.x, tid = threadIdx.x;
    for (int j = tid; j < NBIN; j += 256) h[j] = 0;
    __syncthreads();
    int base = blk * CHUNK;
    for (int i = 0; i < CHUNK / 256; ++i) {
        int e = base + i * 256 + tid;
        if (e < NNZ_E) {
            int r = clampi(row[e], NN - 1);
            atomicAdd(&counts[r], 1);
            atomicAdd(&h[r >> 7], 1);
        }
    }
    __syncthreads();
    for (int j = tid; j < NBIN; j += 256) hist1[j * NBLK1 + blk] = h[j];
}

// Exclusive scan within 256-blocks; bsum[blk] = block total.
__global__ void scan_local_kernel(int* __restrict__ data, int n, int* __restrict__ bsum) {
    __shared__ int s[256];
    int i = blockIdx.x * 256 + threadIdx.x;
    int v = (i < n) ? data[i] : 0;
    s[threadIdx.x] = v;
    __syncthreads();
    for (int off = 1; off < 256; off <<= 1) {
        int t = (threadIdx.x >= off) ? s[threadIdx.x - off] : 0;
        __syncthreads();
        s[threadIdx.x] += t;
        __syncthreads();
    }
    if (i < n) data[i] = s[threadIdx.x] - v;     // exclusive within block
    if (threadIdx.x == 255) bsum[blockIdx.x] = s[threadIdx.x];
}

__global__ void scan_tops_kernel(int* __restrict__ bsum, int m) {  // one block, 512 thr
    __shared__ int s[512];
    int t = threadIdx.x;
    int v = (t < m) ? bsum[t] : 0;
    s[t] = v;
    __syncthreads();
    for (int off = 1; off < 512; off <<= 1) {
        int u = (t >= off) ? s[t - off] : 0;
        __syncthreads();
        s[t] += u;
        __syncthreads();
    }
    if (t < m) bsum[t] = s[t] - v;               // exclusive
}

__global__ void fin_add_kernel(int* __restrict__ data, int n, const int* __restrict__ bsum) {
    int i = blockIdx.x * blockDim.x + threadIdx.x;
    if (i < n) data[i] += bsum[i >> 8];
}

__global__ void fin_counts_kernel(const int* __restrict__ excl,
                                  const int* __restrict__ boff,
                                  int* __restrict__ row_start,
                                  int* __restrict__ cursor) {
    int i = blockIdx.x * blockDim.x + threadIdx.x;
    if (i < NN) {
        int v = excl[i] + boff[i >> 8];
        row_start[i] = v;
        cursor[i] = v;                 // consumed only by big-bin fallback
    }
    if (i == 0) row_start[NN] = NNZ_E;
}

__global__ void bigflag_kernel(const int* __restrict__ row_start, int* __restrict__ bigflag) {
    int k = blockIdx.x * blockDim.x + threadIdx.x;
    if (k < NBIN) {
        int r1 = k * 128 + 128; if (r1 > NN) r1 = NN;
        bigflag[k] = (row_start[r1] - row_start[k * 128] > CAP2) ? 1 : 0;
    }
}

// Pass 1: scatter edges into bin-grouped regions via precomputed per-(bin,blk)
// offsets held in LDS. key = (row&127)<<21 | (col<<5)  (col<<5 < 2^21).
__global__ __launch_bounds__(256) void pass1_kernel(
        const int* __restrict__ row, const int* __restrict__ col,
        const float* __restrict__ a, const float* __restrict__ w,
        const int* __restrict__ hist1_off, const int* __restrict__ bigflag,
        int* __restrict__ cursor,
        unsigned* __restrict__ k1, float* __restrict__ a1, float* __restrict__ w1) {
    __shared__ int bcur[NBIN];
    int blk = blockIdx.x, tid = threadIdx.x;
    for (int j = tid; j < NBIN; j += 256) bcur[j] = hist1_off[j * NBLK1 + blk];
    __syncthreads();
    int base = blk * CHUNK;
    for (int i = 0; i < CHUNK / 256; ++i) {
        int e = base + i * 256 + tid;
        if (e < NNZ_E) {
            int r = clampi(row[e], NN - 1);
            int c = clampi(col[e], NN - 1);
            int bin = r >> 7;
            int pos;
            unsigned key;
            if (bigflag[bin]) {                        // safety path (never in practice)
                pos = atomicAdd(&cursor[r], 1);        // final CSR slot directly
                key = (unsigned)(c << 5);
            } else {
                pos = atomicAdd(&bcur[bin], 1);        // LDS atomic, block-private
                key = ((unsigned)(r & 127) << 21) | (unsigned)(c << 5);
            }
            pos = clampi(pos, NNZ_E - 1);              // hardening: no fault, ever
            k1[pos] = key;
            a1[pos] = a[e];
            w1[pos] = w[e];
        }
    }
}

// Pass 2: one block per bin. In-place within the block-private window.
__global__ __launch_bounds__(256) void pass2_kernel(
        unsigned* __restrict__ k1, float* __restrict__ a1, float* __restrict__ w1,
        const int* __restrict__ row_start, const int* __restrict__ bigflag) {
    int bin = blockIdx.x;
    int r0 = bin << 7;
    int r1 = r0 + 128; if (r1 > NN) r1 = NN;
    int base = row_start[r0];
    int size = row_start[r1] - base;
    // Guards recomputed from row_start (not only bigflag): protects LDS and
    // window bounds even if a producer were wrong.
    if (bigflag[bin] || size > CAP2 || size <= 0 ||
        base < 0 || base + size > NNZ_E) return;

    __shared__ unsigned sK[CAP2];
    __shared__ float sA[CAP2];
    __shared__ float sW[CAP2];
    __shared__ int bino[128];
    int tid = threadIdx.x;
    int rows = r1 - r0;
    for (int j = tid; j < rows; j += 256) bino[j] = clampi(row_start[r0 + j] - base, size);
    for (int i = tid; i < size; i += 256) {
        sK[i] = k1[base + i];
        sA[i] = a1[base + i];
        sW[i] = w1[base + i];
    }
    __syncthreads();                                   // all reads done before writes
    for (int i = tid; i < size; i += 256) {
        unsigned key = sK[i];
        int j = (int)(key >> 21) & 127;
        int p = atomicAdd(&bino[j], 1);
        p = clampi(p, size - 1);                       // hardening: no fault, ever
        k1[base + p] = key & 0x1FFFFFu;                // col<<5
        a1[base + p] = sA[i];
        w1[base + p] = sW[i];
    }
}

__global__ void transpose_in_kernel(const float* __restrict__ x,
                                    float* __restrict__ xt) {
    int i = blockIdx.x * blockDim.x + threadIdx.x;  // i = n*32 + b
    if (i < NB) {
        int n = i >> 5;
        int b = i & 31;
        xt[i] = x[b * NN + n];
    }
}

// One 32-lane half-wave per row; lane = batch column. Atomic-free, unroll-8.
__global__ __launch_bounds__(256) void spmm_kernel(
        const unsigned* __restrict__ colK, const float* __restrict__ vals,
        const int* __restrict__ row_start, const float* __restrict__ in,
        float* __restrict__ out, const float* __restrict__ bias) {
    int t = blockIdx.x * blockDim.x + threadIdx.x;
    int r = t >> 5;
    int b = t & 31;
    if (r >= NN) return;
    int s = row_start[r];
    int e = row_start[r + 1];
    float acc0 = bias ? bias[r] : 0.0f;
    float acc1 = 0.0f;
    int i = s;
    for (; i + 8 <= e; i += 8) {
        unsigned c[8]; float v[8]; float g[8];
#pragma unroll
        for (int j = 0; j < 8; ++j) { c[j] = colK[i + j] & 0x1FFFFFu; v[j] = vals[i + j]; }
#pragma unroll
        for (int j = 0; j < 8; ++j) g[j] = in[c[j] + b];
#pragma unroll
        for (int j = 0; j < 8; ++j) {
            if (j & 1) acc1 += v[j] * g[j]; else acc0 += v[j] * g[j];
        }
    }
    for (; i < e; ++i)
        acc0 += vals[i] * in[(colK[i] & 0x1FFFFFu) + b];
    out[(r << 5) + b] = acc0 + acc1;
}

__global__ void transpose_out_kernel(const float* __restrict__ xt,
                                     float* __restrict__ out) {
    int i = blockIdx.x * blockDim.x + threadIdx.x;  // i = b*N + n (coalesced write)
    if (i < NB) {
        int b = i / NN;
        int n = i - b * NN;
        out[i] = xt[(n << 5) + b];
    }
}

extern "C" void kernel_launch(void* const* d_in, const int* in_sizes, int n_in,
                              void* d_out, int out_size, void* d_ws, size_t ws_size,
                              hipStream_t stream) {
    const float* x        = (const float*)d_in[0];
    const float* adj_vals = (const float*)d_in[1];
    const float* w_vals   = (const float*)d_in[2];
    const float* bias     = (const float*)d_in[3];
    const int*   row      = (const int*)d_in[4];
    const int*   col      = (const int*)d_in[5];
    float* out = (float*)d_out;

    // Workspace (~33 MB; round 3 proved >= 39 MB available)
    unsigned* k1      = (unsigned*)d_ws;          // NNZ_E  (becomes colK<<5)
    float*    a1      = (float*)(k1 + NNZ_E);     // NNZ_E  (sorted A vals)
    float*    w1      = a1 + NNZ_E;               // NNZ_E  (sorted W vals)
    float*    xt      = w1 + NNZ_E;               // NB
    float*    tmp     = xt + NB;                  // NB
    int*   counts     = (int*)(tmp + NB);         // NN
    int*   row_start  = counts + NN;              // NN+1 (+pad)
    int*   cursor     = row_start + NN + 4;       // NN
    int*   bsumA      = cursor + NN;              // 256
    int*   bsumB      = bsumA + 256;              // 512
    int*   bigflag    = bsumB + 512;              // NBIN (+pad)
    int*   hist1      = bigflag + 512;            // NH

    const int BS = 256;
    const int grid_n    = (NN + BS - 1) / BS;     // 196
    const int grid_nb   = (NB + BS - 1) / BS;     // 6250
    const int grid_bin  = (NBIN + BS - 1) / BS;   // 2

    // ---- histograms ----
    zero_counts_kernel<<<grid_n, BS, 0, stream>>>(counts);
    hist_kernel<<<NBLK1, BS, 0, stream>>>(row, counts, hist1);

    // ---- scan per-row counts -> row_start, cursor ----
    scan_local_kernel<<<SCAN_NBLK_A, BS, 0, stream>>>(counts, NN, bsumA);
    scan_tops_kernel<<<1, 512, 0, stream>>>(bsumA, SCAN_NBLK_A);
    fin_counts_kernel<<<grid_n, BS, 0, stream>>>(counts, bsumA, row_start, cursor);
    bigflag_kernel<<<grid_bin, BS, 0, stream>>>(row_start, bigflag);

    // ---- scan (bin,block) matrix -> pass-1 write offsets ----
    scan_local_kernel<<<SCAN_NBLK_B, BS, 0, stream>>>(hist1, NH, bsumB);
    scan_tops_kernel<<<1, 512, 0, stream>>>(bsumB, SCAN_NBLK_B);
    fin_add_kernel<<<SCAN_NBLK_B, BS, 0, stream>>>(hist1, NH, bsumB);

    // ---- two-pass MSD counting sort ----
    pass1_kernel<<<NBLK1, BS, 0, stream>>>(row, col, adj_vals, w_vals,
                                           hist1, bigflag, cursor, k1, a1, w1);
    pass2_kernel<<<NBIN, BS, 0, stream>>>(k1, a1, w1, row_start, bigflag);

    // ---- dense passes ----
    transpose_in_kernel<<<grid_nb, BS, 0, stream>>>(x, xt);
    for (int layer = 0; layer < 3; ++layer) {
        spmm_kernel<<<grid_nb, BS, 0, stream>>>(k1, w1, row_start, xt, tmp, nullptr);
        spmm_kernel<<<grid_nb, BS, 0, stream>>>(k1, a1, row_start, tmp, xt, bias);
    }
    transpose_out_kernel<<<grid_nb, BS, 0, stream>>>(xt, out);
}